// Round 1
// baseline (495.397 us; speedup 1.0000x reference)
//
#include <hip/hip_runtime.h>
#include <hip/hip_bf16.h>

#define DD 768
#define HH 3072
#define BB 64
#define TT 262   // NCLS + P tokens per batch
#define NCLS6 6

typedef __bf16 bf16x8 __attribute__((ext_vector_type(8)));
typedef float f32x4 __attribute__((ext_vector_type(4)));

// class i uses experts {a1,a2}; eouts[j]: first-layer A_FIRST[i*2+j], second-layer A_SECOND[i*2+j]
__device__ __constant__ int A_FIRST[12]  = {0,3, 0,4, 1,3, 1,4, 2,3, 2,4};
__device__ __constant__ int A_SECOND[12] = {3,0, 4,0, 3,1, 4,1, 3,2, 4,2};

__device__ __forceinline__ float gelu_f(float x) {
  return 0.5f * x * (1.0f + erff(x * 0.70710678118654752f));
}

__device__ __forceinline__ void load_lds16(const void* g, void* l) {
  __builtin_amdgcn_global_load_lds(
      (const __attribute__((address_space(1))) void*)g,
      (__attribute__((address_space(3))) void*)l,
      16, 0, 0);
}

// ---------------- cast x (fp32 -> bf16), 4 elems/thread ----------------
__global__ void cast_x_kernel(const float* __restrict__ in, __hip_bfloat16* __restrict__ out, int n4) {
  int i = blockIdx.x * blockDim.x + threadIdx.x;
  if (i < n4) {
    float4 v = ((const float4*)in)[i];
    __hip_bfloat16* o = out + (size_t)i * 4;
    o[0] = __float2bfloat16(v.x);
    o[1] = __float2bfloat16(v.y);
    o[2] = __float2bfloat16(v.z);
    o[3] = __float2bfloat16(v.w);
  }
}

// ---------------- batched transpose + cast: in (R,C) fp32 -> out (C,R) bf16 ----------------
__global__ void transpose_cast(const float* __restrict__ in, __hip_bfloat16* __restrict__ out, int R, int C) {
  __shared__ __hip_bfloat16 tile[32][33];
  size_t boff = (size_t)blockIdx.z * R * C;
  const float* ip = in + boff;
  __hip_bfloat16* op = out + boff;
  int c0 = blockIdx.x * 32, r0 = blockIdx.y * 32;
  int tx = threadIdx.x & 31;
  int ty = threadIdx.x >> 5;  // 0..7
#pragma unroll
  for (int s = 0; s < 4; ++s) {
    int rr = ty * 4 + s;
    tile[rr][tx] = __float2bfloat16(ip[(size_t)(r0 + rr) * C + c0 + tx]);
  }
  __syncthreads();
#pragma unroll
  for (int s = 0; s < 4; ++s) {
    int cc = ty * 4 + s;
    op[(size_t)(c0 + cc) * R + r0 + tx] = tile[tx][cc];
  }
}

// ---------------- gate: sel[i*64+b] = argmax of 2 gate logits (2 = tie -> zero output) ----------------
__global__ void gate_kernel(const float* __restrict__ x, const float* __restrict__ GW, int* __restrict__ sel) {
  int b = blockIdx.x, i = blockIdx.y;
  int lane = threadIdx.x;
  const float* tok = x + (size_t)(b * TT + i) * DD;
  const float* g = GW + (size_t)i * DD * 2;
  float p0 = 0.f, p1 = 0.f;
  for (int k = lane; k < DD; k += 64) {
    float t = tok[k];
    p0 += t * g[k * 2 + 0];
    p1 += t * g[k * 2 + 1];
  }
#pragma unroll
  for (int o = 32; o; o >>= 1) { p0 += __shfl_xor(p0, o); p1 += __shfl_xor(p1, o); }
  if (lane == 0) sel[i * 64 + b] = (p0 > p1) ? 0 : ((p1 > p0) ? 1 : 2);
}

// ---------------- main MFMA GEMM (m97 structure) ----------------
// MODE 0: patch layer1: A=xb (patch rows), B=W1t, out=hidden bf16 (bias+gelu)
// MODE 1: patch layer2: A=hidden,          B=W2t, out=d_out fp32 (bias), patch row remap
// MODE 2: cls layer1  : A=xb tok_i rows,   B=A1t[e], out=hcls bf16 (bias+gelu), combo batched
// MODE 3: cls layer2  : A=hcls[combo],     B=A2t[e], out=d_out fp32 masked by sel
template <int BM, int MODE>
__global__ __launch_bounds__(256, 2)
void gemm_k(const __hip_bfloat16* __restrict__ A,
            const __hip_bfloat16* __restrict__ Bw,
            const float* __restrict__ bias,
            void* __restrict__ Out,
            const int* __restrict__ sel) {
  constexpr int BN = 128;
  constexpr int KDIM = (MODE == 0 || MODE == 2) ? DD : HH;
  constexpr int WAVES_M = (BM == 128) ? 2 : 1;
  constexpr int WAVES_N = 4 / WAVES_M;
  constexpr int MT = BM / (16 * WAVES_M);
  constexpr int NT = BN / (16 * WAVES_N);
  constexpr int CHA = BM * 4 / 256;  // 16B chunks per thread for A tile
  constexpr int CHB = BN * 4 / 256;

  __shared__ __align__(16) char smem[(BM + BN) * 64];
  char* As = smem;
  char* Bs = smem + BM * 64;

  const int tid = threadIdx.x;
  const int lane = tid & 63;
  const int wave = tid >> 6;
  const int q = lane >> 4;
  const int r = lane & 15;
  const int wave_m = wave / WAVES_N;
  const int wave_n = wave % WAVES_N;

  int m0 = 0, n0, combo = 0, cls_i = 0;
  const __hip_bfloat16* Bp = Bw;
  const float* biasp = bias;
  if constexpr (MODE <= 1) {
    m0 = blockIdx.x * BM;
    n0 = blockIdx.y * BN;
  } else {
    n0 = blockIdx.x * BN;
    combo = blockIdx.y;
    cls_i = combo >> 1;
    int e = (MODE == 2) ? A_FIRST[combo] : A_SECOND[combo];
    Bp = Bw + (size_t)e * DD * HH;
    biasp = bias + e * ((MODE == 2) ? HH : DD);
  }

  // staging source pointers (advance 64 B = 32 bf16 of K per iter)
  const char* gA[CHA];
  const char* gB[CHB];
#pragma unroll
  for (int u = 0; u < CHA; ++u) {
    int c = u * 256 + tid;
    int row = c >> 2;
    int within = (c & 3) * 16;
    size_t rowoff;
    if constexpr (MODE == 0) {
      int m = m0 + row;
      int b = m >> 8, p = m & 255;
      rowoff = (size_t)(b * TT + 6 + p) * DD * 2;
    } else if constexpr (MODE == 1) {
      rowoff = (size_t)(m0 + row) * HH * 2;
    } else if constexpr (MODE == 2) {
      rowoff = (size_t)(row * TT + cls_i) * DD * 2;
    } else {
      rowoff = (size_t)(combo * 64 + row) * HH * 2;
    }
    gA[u] = (const char*)A + rowoff + within;
  }
#pragma unroll
  for (int u = 0; u < CHB; ++u) {
    int c = u * 256 + tid;
    int row = c >> 2;
    int within = (c & 3) * 16;
    gB[u] = (const char*)Bp + (size_t)(n0 + row) * KDIM * 2 + within;
  }
  const int wave_base = (tid & ~63) * 16;  // wave*1024 bytes

  f32x4 acc[MT][NT];
#pragma unroll
  for (int i_ = 0; i_ < MT; ++i_)
#pragma unroll
    for (int j_ = 0; j_ < NT; ++j_) acc[i_][j_] = (f32x4){0.f, 0.f, 0.f, 0.f};

  const char* a_rd = As + (wave_m * MT * 16 + r) * 64 + q * 16;
  const char* b_rd = Bs + (wave_n * NT * 16 + r) * 64 + q * 16;

  for (int kt = 0; kt < KDIM / 32; ++kt) {
#pragma unroll
    for (int u = 0; u < CHA; ++u) {
      load_lds16(gA[u], As + u * 4096 + wave_base);
      gA[u] += 64;
    }
#pragma unroll
    for (int u = 0; u < CHB; ++u) {
      load_lds16(gB[u], Bs + u * 4096 + wave_base);
      gB[u] += 64;
    }
    __syncthreads();  // compiler drains vmcnt before s_barrier
    bf16x8 af[MT], bfr[NT];
#pragma unroll
    for (int i_ = 0; i_ < MT; ++i_) af[i_] = *(const bf16x8*)(a_rd + i_ * 1024);
#pragma unroll
    for (int j_ = 0; j_ < NT; ++j_) bfr[j_] = *(const bf16x8*)(b_rd + j_ * 1024);
#pragma unroll
    for (int i_ = 0; i_ < MT; ++i_)
#pragma unroll
      for (int j_ = 0; j_ < NT; ++j_)
        acc[i_][j_] = __builtin_amdgcn_mfma_f32_16x16x32_bf16(af[i_], bfr[j_], acc[i_][j_], 0, 0, 0);
    __syncthreads();
  }

  // epilogue: C/D layout col=lane&15, row=quad*4+reg  [m89/m91-verified]
#pragma unroll
  for (int i_ = 0; i_ < MT; ++i_) {
#pragma unroll
    for (int j_ = 0; j_ < NT; ++j_) {
      int n_g = n0 + (wave_n * NT + j_) * 16 + r;
      float bb = biasp[n_g];
      f32x4 v = acc[i_][j_];
#pragma unroll
      for (int rg = 0; rg < 4; ++rg) {
        int m_g = m0 + (wave_m * MT + i_) * 16 + q * 4 + rg;
        float val = v[rg] + bb;
        if constexpr (MODE == 0) {
          ((__hip_bfloat16*)Out)[(size_t)m_g * HH + n_g] = __float2bfloat16(gelu_f(val));
        } else if constexpr (MODE == 1) {
          int b = m_g >> 8, p = m_g & 255;
          ((float*)Out)[(size_t)(b * TT + 6 + p) * DD + n_g] = val;
        } else if constexpr (MODE == 2) {
          ((__hip_bfloat16*)Out)[(size_t)(combo * 64 + m_g) * HH + n_g] = __float2bfloat16(gelu_f(val));
        } else {
          int s = sel[cls_i * 64 + m_g];
          int j = combo & 1;
          if (s == j) {
            ((float*)Out)[(size_t)(m_g * TT + cls_i) * DD + n_g] = val;
          } else if (j == 0 && s == 2) {
            ((float*)Out)[(size_t)(m_g * TT + cls_i) * DD + n_g] = 0.0f;
          }
        }
      }
    }
  }
}

extern "C" void kernel_launch(void* const* d_in, const int* in_sizes, int n_in,
                              void* d_out, int out_size, void* d_ws, size_t ws_size,
                              hipStream_t stream) {
  const float* x   = (const float*)d_in[0];
  const float* W1  = (const float*)d_in[1];
  const float* b1  = (const float*)d_in[2];
  const float* W2  = (const float*)d_in[3];
  const float* b2  = (const float*)d_in[4];
  const float* A1W = (const float*)d_in[5];
  const float* A1b = (const float*)d_in[6];
  const float* A2W = (const float*)d_in[7];
  const float* A2b = (const float*)d_in[8];
  const float* GW  = (const float*)d_in[9];
  float* out = (float*)d_out;

  char* ws = (char*)d_ws;
  // layout (bytes, 256-aligned):
  __hip_bfloat16* xb   = (__hip_bfloat16*)(ws + 0);          // 64*262*768*2  = 25,755,648
  __hip_bfloat16* W1t  = (__hip_bfloat16*)(ws + 25755648);   // 3072*768*2    =  4,718,592
  __hip_bfloat16* W2t  = (__hip_bfloat16*)(ws + 30474240);   // 768*3072*2    =  4,718,592
  __hip_bfloat16* A1t  = (__hip_bfloat16*)(ws + 35192832);   // 5*3072*768*2  = 23,592,960
  __hip_bfloat16* A2t  = (__hip_bfloat16*)(ws + 58785792);   // 5*768*3072*2  = 23,592,960
  __hip_bfloat16* hcls = (__hip_bfloat16*)(ws + 82378752);   // 12*64*3072*2  =  4,718,592
  int* sel             = (int*)(ws + 87097344);              // 6*64*4 -> pad
  __hip_bfloat16* hid  = (__hip_bfloat16*)(ws + 87099136);   // 16384*3072*2  = 100,663,296
  // total: 187,762,432 bytes

  // preprocessing
  cast_x_kernel<<<12576, 256, 0, stream>>>(x, xb, 3219456);
  transpose_cast<<<dim3(96, 24, 1), 256, 0, stream>>>(W1, W1t, DD, HH);
  transpose_cast<<<dim3(24, 96, 1), 256, 0, stream>>>(W2, W2t, HH, DD);
  transpose_cast<<<dim3(96, 24, 5), 256, 0, stream>>>(A1W, A1t, DD, HH);
  transpose_cast<<<dim3(24, 96, 5), 256, 0, stream>>>(A2W, A2t, HH, DD);
  gate_kernel<<<dim3(64, 6), 64, 0, stream>>>(x, GW, sel);

  // patch MLP
  gemm_k<128, 0><<<dim3(128, 24), 256, 0, stream>>>(xb, W1t, b1, hid, nullptr);
  gemm_k<128, 1><<<dim3(128, 6), 256, 0, stream>>>(hid, W2t, b2, out, nullptr);
  // cls expert path (12 (class,expert-pair-slot) combos batched over blockIdx.y)
  gemm_k<64, 2><<<dim3(24, 12), 256, 0, stream>>>(xb, A1t, A1b, hcls, nullptr);
  gemm_k<64, 3><<<dim3(6, 12), 256, 0, stream>>>(hcls, A2t, A2b, out, sel);
}

// Round 2
// 439.066 us; speedup vs baseline: 1.1283x; 1.1283x over previous
//
#include <hip/hip_runtime.h>
#include <hip/hip_bf16.h>

#define DD 768
#define HH 3072
#define BB 64
#define TT 262   // NCLS + P tokens per batch
#define NCLS6 6

typedef __bf16 bf16x8 __attribute__((ext_vector_type(8)));
typedef float f32x4 __attribute__((ext_vector_type(4)));

// class i uses experts {a1,a2}; eouts[j]: first-layer A_FIRST[i*2+j], second-layer A_SECOND[i*2+j]
__device__ __constant__ int A_FIRST[12]  = {0,3, 0,4, 1,3, 1,4, 2,3, 2,4};
__device__ __constant__ int A_SECOND[12] = {3,0, 4,0, 3,1, 4,1, 3,2, 4,2};

__device__ __forceinline__ float gelu_f(float x) {
  return 0.5f * x * (1.0f + erff(x * 0.70710678118654752f));
}

__device__ __forceinline__ void load_lds16(const void* g, void* l) {
  __builtin_amdgcn_global_load_lds(
      (const __attribute__((address_space(1))) void*)g,
      (__attribute__((address_space(3))) void*)l,
      16, 0, 0);
}

// ---------------- cast x (fp32 -> bf16), 4 elems/thread ----------------
__global__ void cast_x_kernel(const float* __restrict__ in, __hip_bfloat16* __restrict__ out, int n4) {
  int i = blockIdx.x * blockDim.x + threadIdx.x;
  if (i < n4) {
    float4 v = ((const float4*)in)[i];
    __hip_bfloat16* o = out + (size_t)i * 4;
    o[0] = __float2bfloat16(v.x);
    o[1] = __float2bfloat16(v.y);
    o[2] = __float2bfloat16(v.z);
    o[3] = __float2bfloat16(v.w);
  }
}

// ---------------- batched transpose + cast: in (R,C) fp32 -> out (C,R) bf16 ----------------
__global__ void transpose_cast(const float* __restrict__ in, __hip_bfloat16* __restrict__ out, int R, int C) {
  __shared__ __hip_bfloat16 tile[32][33];
  size_t boff = (size_t)blockIdx.z * R * C;
  const float* ip = in + boff;
  __hip_bfloat16* op = out + boff;
  int c0 = blockIdx.x * 32, r0 = blockIdx.y * 32;
  int tx = threadIdx.x & 31;
  int ty = threadIdx.x >> 5;  // 0..7
#pragma unroll
  for (int s = 0; s < 4; ++s) {
    int rr = ty * 4 + s;
    tile[rr][tx] = __float2bfloat16(ip[(size_t)(r0 + rr) * C + c0 + tx]);
  }
  __syncthreads();
#pragma unroll
  for (int s = 0; s < 4; ++s) {
    int cc = ty * 4 + s;
    op[(size_t)(c0 + cc) * R + r0 + tx] = tile[tx][cc];
  }
}

// ---------------- gate: sel[i*64+b] = argmax of 2 gate logits (2 = tie -> zero output) ----------------
__global__ void gate_kernel(const float* __restrict__ x, const float* __restrict__ GW, int* __restrict__ sel) {
  int b = blockIdx.x, i = blockIdx.y;
  int lane = threadIdx.x;
  const float* tok = x + (size_t)(b * TT + i) * DD;
  const float* g = GW + (size_t)i * DD * 2;
  float p0 = 0.f, p1 = 0.f;
  for (int k = lane; k < DD; k += 64) {
    float t = tok[k];
    p0 += t * g[k * 2 + 0];
    p1 += t * g[k * 2 + 1];
  }
#pragma unroll
  for (int o = 32; o; o >>= 1) { p0 += __shfl_xor(p0, o); p1 += __shfl_xor(p1, o); }
  if (lane == 0) sel[i * 64 + b] = (p0 > p1) ? 0 : ((p1 > p0) ? 1 : 2);
}

// ---------------- finalize cls: pick winner combo, sum split-K partials, add bias ----------------
// part layout: part[z][combo][b][d] f32, z<4, combo<12, b<64, d<768
__global__ void finalize_cls(const float* __restrict__ part, const float* __restrict__ A2b,
                             const int* __restrict__ sel, float* __restrict__ out) {
  int t = blockIdx.x * blockDim.x + threadIdx.x;  // 6*64*192
  int d4 = t % 192;
  int b = (t / 192) & 63;
  int cls = t / (192 * 64);
  int s = sel[cls * 64 + b];
  float4 res = make_float4(0.f, 0.f, 0.f, 0.f);
  if (s != 2) {
    int combo = cls * 2 + s;
    const float4* bb = (const float4*)(A2b + (size_t)A_SECOND[combo] * DD);
    res = bb[d4];
#pragma unroll
    for (int z = 0; z < 4; ++z) {
      const float4* p = (const float4*)(part + (((size_t)z * 12 + combo) * 64 + b) * DD);
      float4 v = p[d4];
      res.x += v.x; res.y += v.y; res.z += v.z; res.w += v.w;
    }
  }
  ((float4*)out)[(size_t)(b * TT + cls) * 192 + d4] = res;
}

// ---------------- main MFMA GEMM, BK=64 with XOR-swizzled LDS ----------------
// LDS rows are 128 B (64 bf16 of K). Chunk s (16B) of row holds global chunk s^(row&7).
// Read: lane(q,r) step t reads chunk ((t*4+q)^(r&7)) -> 2 lanes per 4-bank group (free).
// MODE 0: patch layer1: A=xb (patch rows), B=W1t, out=hidden bf16 (bias+gelu), XCD-swizzled grid
// MODE 1: patch layer2: A=hidden,          B=W2t, out=d_out fp32 (bias), patch row remap
// MODE 2: cls layer1  : A=xb tok_i rows,   B=A1t[e], out=hcls bf16 (bias+gelu), combo batched
// MODE 3: cls layer2  : A=hcls[combo],     B=A2t[e], K-split by blockIdx.z, out=part fp32 raw
template <int BM, int MODE>
__global__ __launch_bounds__(256, 2)
void gemm_k(const __hip_bfloat16* __restrict__ A,
            const __hip_bfloat16* __restrict__ Bw,
            const float* __restrict__ bias,
            void* __restrict__ Out,
            const int* __restrict__ sel) {
  constexpr int BN = 128;
  constexpr int KDIM = (MODE == 0 || MODE == 2) ? DD : HH;  // row length of A/B in elems
  constexpr int KITERS = (MODE == 3) ? 12 : KDIM / 64;      // 64 elems (128 B) per iter
  constexpr int WAVES_M = (BM == 128) ? 2 : 1;
  constexpr int WAVES_N = 4 / WAVES_M;
  constexpr int MT = BM / (16 * WAVES_M);
  constexpr int NT = BN / (16 * WAVES_N);
  constexpr int CHA = BM / 32;  // 16B chunks per thread per iter for A tile
  constexpr int CHB = BN / 32;

  __shared__ __align__(16) char smem[(BM + BN) * 128];
  char* As = smem;
  char* Bs = smem + BM * 128;

  const int tid = threadIdx.x;
  const int lane = tid & 63;
  const int wave = tid >> 6;
  const int q = lane >> 4;
  const int r = lane & 15;
  const int wave_m = wave / WAVES_N;
  const int wave_n = wave % WAVES_N;

  int m0 = 0, n0, combo = 0, cls_i = 0, zsp = 0;
  size_t k0b = 0;  // byte offset into K for split-K
  const __hip_bfloat16* Bp = Bw;
  const float* biasp = bias;
  if constexpr (MODE == 0) {
    // XCD-partitioned: xcd owns n-columns [xcd*3, xcd*3+3); n fastest within m
    int l = blockIdx.x;
    int xcd = l & 7;
    int i = l >> 3;        // [0,384)
    int mb = i / 3;
    int nloc = i - mb * 3;
    m0 = mb * BM;
    n0 = (xcd * 3 + nloc) * BN;
  } else if constexpr (MODE == 1) {
    m0 = blockIdx.x * BM;
    n0 = blockIdx.y * BN;
  } else {
    n0 = blockIdx.x * BN;
    combo = blockIdx.y;
    cls_i = combo >> 1;
    int e = (MODE == 2) ? A_FIRST[combo] : A_SECOND[combo];
    Bp = Bw + (size_t)e * DD * HH;
    if constexpr (MODE == 2) biasp = bias + e * HH;
    if constexpr (MODE == 3) { zsp = blockIdx.z; k0b = (size_t)zsp * 768 * 2; }
  }

  // staging source pointers (advance 128 B = 64 bf16 of K per iter)
  const char* gA[CHA];
  const char* gB[CHB];
#pragma unroll
  for (int u = 0; u < CHA; ++u) {
    int c = u * 256 + tid;
    int row = c >> 3;
    int within = ((c & 7) ^ (row & 7)) * 16;  // XOR swizzle
    size_t rowoff;
    if constexpr (MODE == 0) {
      int m = m0 + row;
      int b = m >> 8, p = m & 255;
      rowoff = (size_t)(b * TT + 6 + p) * DD * 2;
    } else if constexpr (MODE == 1) {
      rowoff = (size_t)(m0 + row) * HH * 2;
    } else if constexpr (MODE == 2) {
      rowoff = (size_t)(row * TT + cls_i) * DD * 2;
    } else {
      rowoff = (size_t)(combo * 64 + row) * HH * 2 + k0b;
    }
    gA[u] = (const char*)A + rowoff + within;
  }
#pragma unroll
  for (int u = 0; u < CHB; ++u) {
    int c = u * 256 + tid;
    int row = c >> 3;
    int within = ((c & 7) ^ (row & 7)) * 16;
    gB[u] = (const char*)Bp + (size_t)(n0 + row) * KDIM * 2 + k0b + within;
  }
  const int wave_base = (tid & ~63) * 16;  // wave*1024 bytes

  f32x4 acc[MT][NT];
#pragma unroll
  for (int i_ = 0; i_ < MT; ++i_)
#pragma unroll
    for (int j_ = 0; j_ < NT; ++j_) acc[i_][j_] = (f32x4){0.f, 0.f, 0.f, 0.f};

  const int rx = r & 7;
  const int sa = (q ^ rx) * 16;        // t=0 chunk byte offset
  const char* a_rd0 = As + (wave_m * MT * 16 + r) * 128 + sa;
  const char* a_rd1 = As + (wave_m * MT * 16 + r) * 128 + (sa ^ 64);  // t=1: chunk (4+q)^rx
  const char* b_rd0 = Bs + (wave_n * NT * 16 + r) * 128 + sa;
  const char* b_rd1 = Bs + (wave_n * NT * 16 + r) * 128 + (sa ^ 64);

  for (int kt = 0; kt < KITERS; ++kt) {
#pragma unroll
    for (int u = 0; u < CHA; ++u) {
      load_lds16(gA[u], As + u * 4096 + wave_base);
      gA[u] += 128;
    }
#pragma unroll
    for (int u = 0; u < CHB; ++u) {
      load_lds16(gB[u], Bs + u * 4096 + wave_base);
      gB[u] += 128;
    }
    __syncthreads();
    bf16x8 af0[MT], af1[MT], bf0[NT], bf1[NT];
#pragma unroll
    for (int i_ = 0; i_ < MT; ++i_) {
      af0[i_] = *(const bf16x8*)(a_rd0 + i_ * 2048);
      af1[i_] = *(const bf16x8*)(a_rd1 + i_ * 2048);
    }
#pragma unroll
    for (int j_ = 0; j_ < NT; ++j_) {
      bf0[j_] = *(const bf16x8*)(b_rd0 + j_ * 2048);
      bf1[j_] = *(const bf16x8*)(b_rd1 + j_ * 2048);
    }
#pragma unroll
    for (int i_ = 0; i_ < MT; ++i_)
#pragma unroll
      for (int j_ = 0; j_ < NT; ++j_)
        acc[i_][j_] = __builtin_amdgcn_mfma_f32_16x16x32_bf16(af0[i_], bf0[j_], acc[i_][j_], 0, 0, 0);
#pragma unroll
    for (int i_ = 0; i_ < MT; ++i_)
#pragma unroll
      for (int j_ = 0; j_ < NT; ++j_)
        acc[i_][j_] = __builtin_amdgcn_mfma_f32_16x16x32_bf16(af1[i_], bf1[j_], acc[i_][j_], 0, 0, 0);
    __syncthreads();
  }

  // epilogue: C/D layout col=lane&15, row=quad*4+reg  [m89/m91-verified]
#pragma unroll
  for (int i_ = 0; i_ < MT; ++i_) {
#pragma unroll
    for (int j_ = 0; j_ < NT; ++j_) {
      int n_g = n0 + (wave_n * NT + j_) * 16 + r;
      float bb = 0.f;
      if constexpr (MODE != 3) bb = biasp[n_g];
      f32x4 v = acc[i_][j_];
#pragma unroll
      for (int rg = 0; rg < 4; ++rg) {
        int m_g = m0 + (wave_m * MT + i_) * 16 + q * 4 + rg;
        float val = v[rg] + bb;
        if constexpr (MODE == 0) {
          ((__hip_bfloat16*)Out)[(size_t)m_g * HH + n_g] = __float2bfloat16(gelu_f(val));
        } else if constexpr (MODE == 1) {
          int b = m_g >> 8, p = m_g & 255;
          ((float*)Out)[(size_t)(b * TT + 6 + p) * DD + n_g] = val;
        } else if constexpr (MODE == 2) {
          ((__hip_bfloat16*)Out)[(size_t)(combo * 64 + m_g) * HH + n_g] = __float2bfloat16(gelu_f(val));
        } else {
          ((float*)Out)[(((size_t)zsp * 12 + combo) * 64 + m_g) * DD + n_g] = val;
        }
      }
    }
  }
}

extern "C" void kernel_launch(void* const* d_in, const int* in_sizes, int n_in,
                              void* d_out, int out_size, void* d_ws, size_t ws_size,
                              hipStream_t stream) {
  const float* x   = (const float*)d_in[0];
  const float* W1  = (const float*)d_in[1];
  const float* b1  = (const float*)d_in[2];
  const float* W2  = (const float*)d_in[3];
  const float* b2  = (const float*)d_in[4];
  const float* A1W = (const float*)d_in[5];
  const float* A1b = (const float*)d_in[6];
  const float* A2W = (const float*)d_in[7];
  const float* A2b = (const float*)d_in[8];
  const float* GW  = (const float*)d_in[9];
  float* out = (float*)d_out;

  char* ws = (char*)d_ws;
  // layout (bytes, 256-aligned):
  __hip_bfloat16* xb   = (__hip_bfloat16*)(ws + 0);          // 64*262*768*2  = 25,755,648
  __hip_bfloat16* W1t  = (__hip_bfloat16*)(ws + 25755648);   // 3072*768*2    =  4,718,592
  __hip_bfloat16* W2t  = (__hip_bfloat16*)(ws + 30474240);   // 768*3072*2    =  4,718,592
  __hip_bfloat16* A1t  = (__hip_bfloat16*)(ws + 35192832);   // 5*3072*768*2  = 23,592,960
  __hip_bfloat16* A2t  = (__hip_bfloat16*)(ws + 58785792);   // 5*768*3072*2  = 23,592,960
  __hip_bfloat16* hcls = (__hip_bfloat16*)(ws + 82378752);   // 12*64*3072*2  =  4,718,592
  int* sel             = (int*)(ws + 87097344);              // 6*64*4 -> pad
  __hip_bfloat16* hid  = (__hip_bfloat16*)(ws + 87099136);   // 16384*3072*2  = 100,663,296
  // part aliases A1t region (A1t is dead once cls layer1 completes; stream is serial):
  float* part          = (float*)(ws + 35192832);            // 4*12*64*768*4 =  9,437,184
  // total: 187,762,432 bytes

  // preprocessing
  cast_x_kernel<<<12576, 256, 0, stream>>>(x, xb, 3219456);
  transpose_cast<<<dim3(96, 24, 1), 256, 0, stream>>>(W1, W1t, DD, HH);
  transpose_cast<<<dim3(24, 96, 1), 256, 0, stream>>>(W2, W2t, HH, DD);
  transpose_cast<<<dim3(96, 24, 5), 256, 0, stream>>>(A1W, A1t, DD, HH);
  transpose_cast<<<dim3(24, 96, 5), 256, 0, stream>>>(A2W, A2t, HH, DD);
  gate_kernel<<<dim3(64, 6), 64, 0, stream>>>(x, GW, sel);

  // cls expert path first (frees A1t region for part before cls layer2)
  gemm_k<64, 2><<<dim3(24, 12), 256, 0, stream>>>(xb, A1t, A1b, hcls, nullptr);
  gemm_k<64, 3><<<dim3(6, 12, 4), 256, 0, stream>>>(hcls, A2t, nullptr, part, nullptr);
  finalize_cls<<<288, 256, 0, stream>>>(part, A2b, sel, out);

  // patch MLP
  gemm_k<128, 0><<<3072, 256, 0, stream>>>(xb, W1t, b1, hid, nullptr);
  gemm_k<128, 1><<<dim3(128, 6), 256, 0, stream>>>(hid, W2t, b2, out, nullptr);
}